// Round 3
// baseline (733.731 us; speedup 1.0000x reference)
//
#include <hip/hip_runtime.h>

#define BB 4096
#define NN 32768
#define LL 12
#define KK 64
#define SS (LL * KK)        // 768 slots

constexpr int TPB   = 256;              // 4 waves/block
constexpr int NBLK  = 2048;             // 2 rows/block, 1 half-row per wave
constexpr int NWRD  = NN / 32;          // 1024 bitmap words
constexpr int HF4   = NN / 4 / 2;       // 4096 float4 per half-row
constexpr int NB    = HF4 / 64 / 4;     // 16 batches of 4 float4 per lane

__global__ __launch_bounds__(TPB) void hsm_stream(
    const float* __restrict__ x,
    const int* __restrict__ brother,
    const int* __restrict__ p_y,
    float* __restrict__ partials) {

    __shared__ unsigned bmp[NWRD];      // 4 KB needed-column bitmap (row-global)
    __shared__ int      pfx[NWRD];      // 4 KB exclusive popcount prefix
    __shared__ float    gath[2][SS];    // 6 KB compacted values, one per row
    __shared__ int      strip[4];

    const int tid  = threadIdx.x;
    const int w    = tid >> 6;          // wave 0..3
    const int lane = tid & 63;
    const int rloc = w >> 1;            // row-in-block 0/1
    const int half = w & 1;             // half-row 0/1
    const int row  = blockIdx.x * 2 + rloc;

    // ---- build bitmap (union of all 768 needed columns) ----
    #pragma unroll
    for (int i = 0; i < NWRD / TPB; ++i) bmp[i * TPB + tid] = 0u;
    __syncthreads();
    #pragma unroll
    for (int j = 0; j < SS / TPB; ++j) {
        const int c = brother[j * TPB + tid];
        atomicOr(&bmp[c >> 5], 1u << (c & 31));
    }
    __syncthreads();

    // ---- exclusive popcount prefix, all 4 waves (256 words each) ----
    {
        const int base = w * 256 + lane * 4;
        int c0 = __popc(bmp[base]), c1 = __popc(bmp[base + 1]);
        int c2 = __popc(bmp[base + 2]), c3 = __popc(bmp[base + 3]);
        const int tot = c0 + c1 + c2 + c3;
        int incl = tot;
        #pragma unroll
        for (int o = 1; o < 64; o <<= 1) {
            const int t = __shfl_up(incl, o);
            if (lane >= o) incl += t;
        }
        if (lane == 63) strip[w] = incl;
        __syncthreads();
        int run = incl - tot;
        for (int j = 0; j < w; ++j) run += strip[j];
        pfx[base] = run;  run += c0;
        pfx[base + 1] = run; run += c1;
        pfx[base + 2] = run; run += c2;
        pfx[base + 3] = run;
    }
    __syncthreads();

    // ---- stream this wave's half-row: 2x4 float4 ping-pong, no barriers ----
    const int   sh  = (lane & 7) << 2;            // nibble shift (per-thread const)
    const unsigned msk = (1u << sh) - 1u;
    const float4* xh = (const float4*)(x + (size_t)row * NN) + half * HF4;
    float* g = gath[rloc];
    const int wbase = half * (NWRD / 2);          // bitmap word base of this half

#define LOAD4(buf, bt) do {                                         \
    _Pragma("unroll")                                               \
    for (int u = 0; u < 4; ++u)                                     \
        buf[u] = xh[(((bt) * 4 + u) * 64) + lane];                  \
} while (0)

#define SCAT4(buf, bt) do {                                         \
    _Pragma("unroll")                                               \
    for (int u = 0; u < 4; ++u) {                                   \
        const int bi = (bt) * 4 + u;                                \
        const int wi = wbase + bi * 8 + (lane >> 3);                \
        const unsigned wrd = bmp[wi];                               \
        const unsigned nib = (wrd >> sh) & 0xFu;                    \
        if (nib) {                                                  \
            int r = pfx[wi] + __popc(wrd & msk);                    \
            if (nib & 1u) g[r++] = buf[u].x;                        \
            if (nib & 2u) g[r++] = buf[u].y;                        \
            if (nib & 4u) g[r++] = buf[u].z;                        \
            if (nib & 8u) g[r]   = buf[u].w;                        \
        }                                                           \
    }                                                               \
} while (0)

    {
        float4 va[4], vb[4];
        LOAD4(va, 0);
        #pragma unroll 1
        for (int it = 0; it < NB; it += 2) {
            LOAD4(vb, it + 1);
            SCAT4(va, it);
            if (it + 2 < NB) LOAD4(va, it + 2);
            SCAT4(vb, it + 1);
        }
    }
    __syncthreads();    // both halves of each row scattered

    // ---- softmax: waves (rloc,0)/(rloc,1) split the 12 l's for row rloc ----
    int colv[LL / 2];
    #pragma unroll
    for (int j = 0; j < LL / 2; ++j)
        colv[j] = brother[(half * (LL / 2) + j) * KK + lane];

    float my = 0.f;
    #pragma unroll
    for (int j = 0; j < LL / 2; ++j) {
        const int l  = half * (LL / 2) + j;
        const int c  = colv[j];
        const int lab = __ffsll(__ballot(c == p_y[l])) - 1;
        const unsigned wrd = bmp[c >> 5];
        const int ds = pfx[c >> 5] + __popc(wrd & ((1u << (c & 31)) - 1u));
        const float vv = g[ds];
        float mx = vv;
        #pragma unroll
        for (int o = 32; o > 0; o >>= 1) mx = fmaxf(mx, __shfl_xor(mx, o));
        float s = __expf(vv - mx);
        #pragma unroll
        for (int o = 32; o > 0; o >>= 1) s += __shfl_xor(s, o);
        const float loss = mx + __logf(s) - __shfl(vv, lab);
        if (lane == l) my = loss;
    }
    if ((lane >> 3) == 0 || true) {      // keep simple: predicate below
        if (lane >= half * (LL / 2) && lane < half * (LL / 2) + LL / 2)
            partials[lane * BB + row] = my;
    }
}

// Per-l sum over rows, mean over B, then sum over l (matches reference order).
__global__ __launch_bounds__(256) void hsm_final(
    const float* __restrict__ partials, float* __restrict__ out) {
    const int w = threadIdx.x >> 6, lane = threadIdx.x & 63;
    __shared__ float red[LL];
    #pragma unroll
    for (int j = 0; j < 3; ++j) {
        const int l = w + 4 * j;
        float s = 0.f;
        for (int i = lane; i < BB; i += 64) s += partials[l * BB + i];
        #pragma unroll
        for (int o = 32; o > 0; o >>= 1) s += __shfl_xor(s, o);
        if (lane == 0) red[l] = s / (float)BB;
    }
    __syncthreads();
    if (threadIdx.x == 0) {
        float t = 0.f;
        #pragma unroll
        for (int i = 0; i < LL; ++i) t += red[i];
        out[0] = t;
    }
}

extern "C" void kernel_launch(void* const* d_in, const int* in_sizes, int n_in,
                              void* d_out, int out_size, void* d_ws, size_t ws_size,
                              hipStream_t stream) {
    const float* x       = (const float*)d_in[0];
    const int*   brother = (const int*)d_in[1];
    const int*   p_y     = (const int*)d_in[2];
    // d_in[3] = y : unused by the reference
    float* out      = (float*)d_out;
    float* partials = (float*)d_ws;     // LL*BB floats = 192 KB << ws_size

    hsm_stream<<<NBLK, TPB, 0, stream>>>(x, brother, p_y, partials);
    hsm_final<<<1, 256, 0, stream>>>(partials, out);
}